// Round 5
// baseline (310.394 us; speedup 1.0000x reference)
//
#include <hip/hip_runtime.h>
#include <math.h>

static inline size_t ws_align(size_t x) { return (x + 255) & ~size_t(255); }

__device__ inline unsigned int bf16rne(float f) {
    unsigned int u = __float_as_uint(f);
    u += 0x7FFFu + ((u >> 16) & 1u);
    return u >> 16;
}
__device__ inline float bf2f(unsigned short u) {
    return __uint_as_float(((unsigned int)u) << 16);
}

// ---------------- zero deg ----------------
__global__ void zero_kernel(int* __restrict__ p, int n) {
    int i = blockIdx.x * blockDim.x + threadIdx.x;
    if (i < n) p[i] = 0;
}

// ---------------- degree histogram + per-edge slot ----------------
__global__ void deg_pos_kernel(const int* __restrict__ dst, int E,
                               int* __restrict__ deg, int* __restrict__ pos) {
    int e = blockIdx.x * blockDim.x + threadIdx.x;
    if (e < E) pos[e] = atomicAdd(&deg[dst[e]], 1);
}

__global__ void dinv_kernel(const int* __restrict__ deg, float* __restrict__ dinv, int n) {
    int i = blockIdx.x * blockDim.x + threadIdx.x;
    if (i < n) dinv[i] = rsqrtf((float)(deg[i] + 1));  // +1 self-loop
}

// ---------------- exclusive scan of deg -> rowptr (1024 elems/block) ----------
__global__ void scan1_kernel(const int* __restrict__ deg, int* __restrict__ bsum, int n) {
    __shared__ int sdata[256];
    int base = blockIdx.x * 1024;
    int sum = 0;
    for (int i = threadIdx.x; i < 1024; i += 256) {
        int idx = base + i;
        if (idx < n) sum += deg[idx];
    }
    sdata[threadIdx.x] = sum;
    __syncthreads();
    for (int s = 128; s > 0; s >>= 1) {
        if (threadIdx.x < s) sdata[threadIdx.x] += sdata[threadIdx.x + s];
        __syncthreads();
    }
    if (threadIdx.x == 0) bsum[blockIdx.x] = sdata[0];
}

__global__ void scan2_kernel(int* __restrict__ bsum, int nb) {  // nb <= 256, 1 block
    __shared__ int sdata[256];
    int v = (threadIdx.x < nb) ? bsum[threadIdx.x] : 0;
    sdata[threadIdx.x] = v;
    __syncthreads();
    for (int off = 1; off < 256; off <<= 1) {
        int t = (threadIdx.x >= off) ? sdata[threadIdx.x - off] : 0;
        __syncthreads();
        sdata[threadIdx.x] += t;
        __syncthreads();
    }
    if (threadIdx.x < nb) bsum[threadIdx.x] = sdata[threadIdx.x] - v;  // exclusive
}

__global__ void scan3_kernel(const int* __restrict__ deg, const int* __restrict__ bsum,
                             int* __restrict__ rowptr, int n) {
    __shared__ int ssum[256];
    int base = blockIdx.x * 1024 + threadIdx.x * 4;
    int v[4];
    int s = 0;
#pragma unroll
    for (int k = 0; k < 4; ++k) {
        int idx = base + k;
        v[k] = (idx < n) ? deg[idx] : 0;
        s += v[k];
    }
    ssum[threadIdx.x] = s;
    __syncthreads();
    for (int off = 1; off < 256; off <<= 1) {
        int t = (threadIdx.x >= off) ? ssum[threadIdx.x - off] : 0;
        __syncthreads();
        ssum[threadIdx.x] += t;
        __syncthreads();
    }
    int ex = (threadIdx.x > 0 ? ssum[threadIdx.x - 1] : 0) + bsum[blockIdx.x];
#pragma unroll
    for (int k = 0; k < 4; ++k) {
        int idx = base + k;
        if (idx < n) rowptr[idx] = ex;
        ex += v[k];
    }
}

// ---------------- CSR fill (no atomic): adjw[rowptr[d]+pos[e]] = {src, wgt} --
__global__ void fill_kernel(const int* __restrict__ src, const int* __restrict__ dst,
                            const int* __restrict__ pos, const float* __restrict__ dinv,
                            const int* __restrict__ rowptr, int2* __restrict__ adjw, int E) {
    int e = blockIdx.x * blockDim.x + threadIdx.x;
    if (e >= E) return;
    int s = src[e], d = dst[e];
    int p = rowptr[d] + pos[e];
    adjw[p] = make_int2(s, __float_as_int(dinv[s] * dinv[d]));
}

// ---------------- dense transform: W cols in VGPRs, readlane row broadcast ---
// lane owns output col `lane`; RPI rows per wave, interleaved for ILP.
// Output: packed bf16 (even lanes store {col l, col l+1} as one u32).
template <int FIN, int FOUT, bool RELU_IN, int RPI>
__global__ void gemm_bf16_kernel(const float* __restrict__ in, const float* __restrict__ W,
                                 unsigned int* __restrict__ hb, int n) {
    int lane = threadIdx.x & 63;
    int gwave = blockIdx.x * (blockDim.x >> 6) + (threadIdx.x >> 6);
    float w[FIN];
#pragma unroll
    for (int k = 0; k < FIN; ++k)
        w[k] = (lane < FOUT) ? W[k * FOUT + lane] : 0.0f;

    int r0 = gwave * RPI;
    if (r0 >= n) return;
    float v[RPI];
    float acc[RPI];
#pragma unroll
    for (int j = 0; j < RPI; ++j) {
        int row = r0 + j;
        int rr = (row < n) ? row : (n - 1);
        float t = in[(size_t)rr * FIN + lane];
        if (RELU_IN) t = fmaxf(t, 0.0f);
        v[j] = t;
        acc[j] = 0.0f;
    }
#pragma unroll
    for (int k = 0; k < FIN; ++k) {
#pragma unroll
        for (int j = 0; j < RPI; ++j) {
            float bc = __uint_as_float(__builtin_amdgcn_readlane(__float_as_uint(v[j]), k));
            acc[j] = fmaf(bc, w[k], acc[j]);
        }
    }
#pragma unroll
    for (int j = 0; j < RPI; ++j) {
        int row = r0 + j;
        float po = __shfl_xor(acc[j], 1, 64);  // partner column
        if (row < n && ((lane & 1) == 0) && lane < FOUT) {
            unsigned int packed = bf16rne(acc[j]) | (bf16rne(po) << 16);
            hb[(size_t)row * (FOUT / 2) + (lane >> 1)] = packed;
        }
    }
}

// ---------------- gather-aggregate: quarter (16 lanes) per node, bf16 h ------
// out[v] = h[v]*dinv[v]^2 + b + sum_{e: dst=v} h[src_e] * wgt_e   (fp32 accum)
template <int F>  // F % 4 == 0, F <= 64
__global__ void gather_bf16_kernel(const int* __restrict__ rowptr, const int* __restrict__ deg,
                                   const int2* __restrict__ adjw, const ushort4* __restrict__ h4,
                                   const float* __restrict__ dinv, const float* __restrict__ b,
                                   float* __restrict__ out, int n) {
    const int F4 = F / 4;
    int lane = threadIdx.x & 63;
    int wid = threadIdx.x >> 6;
    int q = lane >> 4;
    int i = lane & 15;
    int node = blockIdx.x * 16 + wid * 4 + q;
    if (node >= n) return;
    const bool fv = (i < F4);
    float di = dinv[node];
    float4 acc = make_float4(0.f, 0.f, 0.f, 0.f);
    if (fv) {
        ushort4 hv = h4[(size_t)node * F4 + i];
        float4 bv = ((const float4*)b)[i];
        float d2 = di * di;
        acc.x = fmaf(bf2f(hv.x), d2, bv.x);
        acc.y = fmaf(bf2f(hv.y), d2, bv.y);
        acc.z = fmaf(bf2f(hv.z), d2, bv.z);
        acc.w = fmaf(bf2f(hv.w), d2, bv.w);
    }
    int r0 = rowptr[node];
    int cnt = deg[node];
    for (int j0 = 0; j0 < cnt; j0 += 16) {
#pragma unroll
        for (int t = 0; t < 16; ++t) {
            int idx = j0 + t;
            if (idx < cnt) {              // quarter-uniform guard
                int2 ew = adjw[r0 + idx]; // broadcast within quarter
                float wt = __int_as_float(ew.y);
                if (fv) {
                    ushort4 hv = h4[(size_t)ew.x * F4 + i];
                    acc.x = fmaf(bf2f(hv.x), wt, acc.x);
                    acc.y = fmaf(bf2f(hv.y), wt, acc.y);
                    acc.z = fmaf(bf2f(hv.z), wt, acc.z);
                    acc.w = fmaf(bf2f(hv.w), wt, acc.w);
                }
            }
        }
    }
    if (fv) ((float4*)out)[(size_t)node * F4 + i] = acc;
}

// ---------------- log_softmax over C cols, one wave per row ------------------
template <int C>
__global__ void logsoftmax_kernel(float* __restrict__ out, int n) {
    int wave = threadIdx.x >> 6;
    int lane = threadIdx.x & 63;
    int row = blockIdx.x * 4 + wave;
    if (row >= n) return;
    float v = (lane < C) ? out[(size_t)row * C + lane] : -INFINITY;
    float m = v;
#pragma unroll
    for (int off = 32; off >= 1; off >>= 1) m = fmaxf(m, __shfl_xor(m, off, 64));
    float e = (lane < C) ? expf(v - m) : 0.0f;
    float s = e;
#pragma unroll
    for (int off = 32; off >= 1; off >>= 1) s += __shfl_xor(s, off, 64);
    if (lane < C) out[(size_t)row * C + lane] = v - m - logf(s);
}

extern "C" void kernel_launch(void* const* d_in, const int* in_sizes, int n_in,
                              void* d_out, int out_size, void* d_ws, size_t ws_size,
                              hipStream_t stream) {
    const float* x  = (const float*)d_in[0];
    const int*   ei = (const int*)d_in[1];
    const float* W0 = (const float*)d_in[2];
    const float* b0 = (const float*)d_in[3];
    const float* W1 = (const float*)d_in[4];
    const float* b1 = (const float*)d_in[5];
    const float* W2 = (const float*)d_in[6];
    const float* b2 = (const float*)d_in[7];
    float* out = (float*)d_out;

    const int H   = in_sizes[3];            // 64
    const int FIN = in_sizes[2] / H;        // 64
    const int n   = in_sizes[0] / FIN;      // 50000
    const int E   = in_sizes[1] / 2;        // 800000
    (void)FIN;

    const int* srcp = ei;
    const int* dstp = ei + E;

    char* ws = (char*)d_ws;
    size_t off = 0;
    int*   deg    = (int*)(ws + off);   off += ws_align((size_t)n * 4);
    int*   rowptr = (int*)(ws + off);   off += ws_align((size_t)n * 4);
    int*   bsum   = (int*)(ws + off);   off += ws_align(256 * 4);
    float* dinv   = (float*)(ws + off); off += ws_align((size_t)n * 4);
    int*   pos    = (int*)(ws + off);   off += ws_align((size_t)E * 4);
    int2*  adjw   = (int2*)(ws + off);  off += ws_align((size_t)E * 8);
    unsigned int* hb = (unsigned int*)(ws + off); off += ws_align((size_t)n * H * 2);
    float* bufA   = (float*)(ws + off); off += ws_align((size_t)n * H * 4);

    // CSR build (deg zeroed by kernel; pos needs no init)
    zero_kernel<<<(n + 255) / 256, 256, 0, stream>>>(deg, n);
    deg_pos_kernel<<<(E + 255) / 256, 256, 0, stream>>>(dstp, E, deg, pos);
    dinv_kernel<<<(n + 255) / 256, 256, 0, stream>>>(deg, dinv, n);
    int nscan = (n + 1023) / 1024;  // 49
    scan1_kernel<<<nscan, 256, 0, stream>>>(deg, bsum, n);
    scan2_kernel<<<1, 256, 0, stream>>>(bsum, nscan);
    scan3_kernel<<<nscan, 256, 0, stream>>>(deg, bsum, rowptr, n);
    fill_kernel<<<(E + 255) / 256, 256, 0, stream>>>(srcp, dstp, pos, dinv, rowptr, adjw, E);

    const int RPI = 16;  // rows per wave in gemm
    int gemm_grid = (n + 4 * RPI - 1) / (4 * RPI);   // 4 waves/block
    int node_grid = (n + 15) / 16;                   // 16 nodes/block

    // layer 0
    gemm_bf16_kernel<64, 64, false, RPI><<<gemm_grid, 256, 0, stream>>>(x, W0, hb, n);
    gather_bf16_kernel<64><<<node_grid, 256, 0, stream>>>(rowptr, deg, adjw, (const ushort4*)hb, dinv, b0, bufA, n);
    // layer 1
    gemm_bf16_kernel<64, 64, true, RPI><<<gemm_grid, 256, 0, stream>>>(bufA, W1, hb, n);
    gather_bf16_kernel<64><<<node_grid, 256, 0, stream>>>(rowptr, deg, adjw, (const ushort4*)hb, dinv, b1, bufA, n);
    // layer 2
    gemm_bf16_kernel<64, 40, true, RPI><<<gemm_grid, 256, 0, stream>>>(bufA, W2, hb, n);
    gather_bf16_kernel<40><<<node_grid, 256, 0, stream>>>(rowptr, deg, adjw, (const ushort4*)hb, dinv, b2, out, n);
    logsoftmax_kernel<40><<<(n + 3) / 4, 256, 0, stream>>>(out, n);
}

// Round 6
// 222.394 us; speedup vs baseline: 1.3957x; 1.3957x over previous
//
#include <hip/hip_runtime.h>
#include <math.h>

static inline size_t ws_align(size_t x) { return (x + 255) & ~size_t(255); }

typedef float f32x4 __attribute__((ext_vector_type(4)));
typedef short bf16x8 __attribute__((ext_vector_type(8)));

__device__ inline unsigned int bf16rne(float f) {
    unsigned int u = __float_as_uint(f);
    u += 0x7FFFu + ((u >> 16) & 1u);
    return u >> 16;
}
__device__ inline float bf2f(unsigned short u) {
    return __uint_as_float(((unsigned int)u) << 16);
}

// ---------------- zero deg ----------------
__global__ void zero_kernel(int* __restrict__ p, int n) {
    int i = blockIdx.x * blockDim.x + threadIdx.x;
    if (i < n) p[i] = 0;
}

// ---------------- degree histogram + per-edge slot ----------------
__global__ void deg_pos_kernel(const int* __restrict__ dst, int E,
                               int* __restrict__ deg, int* __restrict__ pos) {
    int e = blockIdx.x * blockDim.x + threadIdx.x;
    if (e < E) pos[e] = atomicAdd(&deg[dst[e]], 1);
}

__global__ void dinv_kernel(const int* __restrict__ deg, float* __restrict__ dinv, int n) {
    int i = blockIdx.x * blockDim.x + threadIdx.x;
    if (i < n) dinv[i] = rsqrtf((float)(deg[i] + 1));  // +1 self-loop
}

// ---------------- exclusive scan of deg -> rowptr (1024 elems/block) ----------
__global__ void scan1_kernel(const int* __restrict__ deg, int* __restrict__ bsum, int n) {
    __shared__ int sdata[256];
    int base = blockIdx.x * 1024;
    int sum = 0;
    for (int i = threadIdx.x; i < 1024; i += 256) {
        int idx = base + i;
        if (idx < n) sum += deg[idx];
    }
    sdata[threadIdx.x] = sum;
    __syncthreads();
    for (int s = 128; s > 0; s >>= 1) {
        if (threadIdx.x < s) sdata[threadIdx.x] += sdata[threadIdx.x + s];
        __syncthreads();
    }
    if (threadIdx.x == 0) bsum[blockIdx.x] = sdata[0];
}

__global__ void scan2_kernel(int* __restrict__ bsum, int nb) {  // nb <= 256, 1 block
    __shared__ int sdata[256];
    int v = (threadIdx.x < nb) ? bsum[threadIdx.x] : 0;
    sdata[threadIdx.x] = v;
    __syncthreads();
    for (int off = 1; off < 256; off <<= 1) {
        int t = (threadIdx.x >= off) ? sdata[threadIdx.x - off] : 0;
        __syncthreads();
        sdata[threadIdx.x] += t;
        __syncthreads();
    }
    if (threadIdx.x < nb) bsum[threadIdx.x] = sdata[threadIdx.x] - v;  // exclusive
}

__global__ void scan3_kernel(const int* __restrict__ deg, const int* __restrict__ bsum,
                             int* __restrict__ rowptr, int n) {
    __shared__ int ssum[256];
    int base = blockIdx.x * 1024 + threadIdx.x * 4;
    int v[4];
    int s = 0;
#pragma unroll
    for (int k = 0; k < 4; ++k) {
        int idx = base + k;
        v[k] = (idx < n) ? deg[idx] : 0;
        s += v[k];
    }
    ssum[threadIdx.x] = s;
    __syncthreads();
    for (int off = 1; off < 256; off <<= 1) {
        int t = (threadIdx.x >= off) ? ssum[threadIdx.x - off] : 0;
        __syncthreads();
        ssum[threadIdx.x] += t;
        __syncthreads();
    }
    int ex = (threadIdx.x > 0 ? ssum[threadIdx.x - 1] : 0) + bsum[blockIdx.x];
#pragma unroll
    for (int k = 0; k < 4; ++k) {
        int idx = base + k;
        if (idx < n) rowptr[idx] = ex;
        ex += v[k];
    }
}

// ---------------- CSR fill (no atomic): adjw[rowptr[d]+pos[e]] = {src, wgt} --
__global__ void fill_kernel(const int* __restrict__ src, const int* __restrict__ dst,
                            const int* __restrict__ pos, const float* __restrict__ dinv,
                            const int* __restrict__ rowptr, int2* __restrict__ adjw, int E) {
    int e = blockIdx.x * blockDim.x + threadIdx.x;
    if (e >= E) return;
    int s = src[e], d = dst[e];
    int p = rowptr[d] + pos[e];
    adjw[p] = make_int2(s, __float_as_int(dinv[s] * dinv[d]));
}

// ---------------- W -> MFMA B-fragment layout (bf16), zero-padded ------------
// wf[((ct*2+kh)*64 + lane)*8 + j] = bf16(W[k*FOUT + col]), k=kh*32+(lane>>4)*8+j,
// col = ct*16 + (lane&15); 0 if col >= FOUT.
template <int FOUT, int CT>
__global__ void wconv_kernel(const float* __restrict__ W, unsigned short* __restrict__ wf) {
    for (int idx = threadIdx.x; idx < CT * 2 * 64 * 8; idx += 256) {
        int j = idx & 7;
        int lane = (idx >> 3) & 63;
        int kh = (idx >> 9) & 1;
        int ct = idx >> 10;
        int k = kh * 32 + ((lane >> 4) * 8) + j;
        int col = ct * 16 + (lane & 15);
        float v = (col < FOUT) ? W[k * FOUT + col] : 0.0f;
        wf[idx] = (unsigned short)bf16rne(v);
    }
}

// ---------------- MFMA dense transform: fp32 in -> bf16 packed out ----------
// FIN fixed at 64. One wave = 16-row tile x FOUT cols; MT tiles per wave.
template <int FOUT, int CT, bool RELU_IN, int MT>
__global__ void gemm_mfma_kernel(const float* __restrict__ in, const unsigned short* __restrict__ wf,
                                 unsigned int* __restrict__ hb, int n) {
    int lane = threadIdx.x & 63;
    int tile0 = (blockIdx.x * 4 + (threadIdx.x >> 6)) * MT;
    if (tile0 * 16 >= n) return;
    bf16x8 bfrag[CT][2];
#pragma unroll
    for (int ct = 0; ct < CT; ++ct)
#pragma unroll
        for (int kh = 0; kh < 2; ++kh)
            bfrag[ct][kh] = *(const bf16x8*)(wf + ((size_t)(ct * 2 + kh) * 64 + lane) * 8);

    int rloc = lane & 15;   // A row within tile
    int koct = lane >> 4;   // k octet 0..3
    for (int t = 0; t < MT; ++t) {
        int rbase = (tile0 + t) * 16;
        if (rbase >= n) break;
        int r = rbase + rloc;
        int rc = (r < n) ? r : (n - 1);
        const float* ap = in + (size_t)rc * 64 + koct * 8;
        float av[16];
        *(float4*)(av + 0)  = *(const float4*)(ap + 0);
        *(float4*)(av + 4)  = *(const float4*)(ap + 4);
        *(float4*)(av + 8)  = *(const float4*)(ap + 32);
        *(float4*)(av + 12) = *(const float4*)(ap + 36);
        bf16x8 af0, af1;
#pragma unroll
        for (int j = 0; j < 8; ++j) {
            float v0 = av[j], v1 = av[8 + j];
            if (RELU_IN) { v0 = fmaxf(v0, 0.0f); v1 = fmaxf(v1, 0.0f); }
            af0[j] = (short)bf16rne(v0);
            af1[j] = (short)bf16rne(v1);
        }
#pragma unroll
        for (int ct = 0; ct < CT; ++ct) {
            f32x4 acc = {0.0f, 0.0f, 0.0f, 0.0f};
            acc = __builtin_amdgcn_mfma_f32_16x16x32_bf16(af0, bfrag[ct][0], acc, 0, 0, 0);
            acc = __builtin_amdgcn_mfma_f32_16x16x32_bf16(af1, bfrag[ct][1], acc, 0, 0, 0);
            int col = ct * 16 + rloc;  // D col = lane&15
#pragma unroll
            for (int reg = 0; reg < 4; ++reg) {
                int row = rbase + koct * 4 + reg;  // D row = (lane>>4)*4+reg
                float v = acc[reg];
                float po = __shfl_xor(v, 1, 64);   // partner column (lane^1)
                if (row < n && ((lane & 1) == 0) && col < FOUT) {
                    hb[((size_t)row * FOUT + col) >> 1] = bf16rne(v) | (bf16rne(po) << 16);
                }
            }
        }
    }
}

// ---------------- gather-aggregate: quarter (16 lanes) per node, bf16 h ------
// out[v] = h[v]*dinv[v]^2 + b + sum_{e: dst=v} h[src_e] * wgt_e   (fp32 accum)
template <int F>  // F % 4 == 0, F <= 64
__global__ void gather_bf16_kernel(const int* __restrict__ rowptr, const int* __restrict__ deg,
                                   const int2* __restrict__ adjw, const ushort4* __restrict__ h4,
                                   const float* __restrict__ dinv, const float* __restrict__ b,
                                   float* __restrict__ out, int n) {
    const int F4 = F / 4;
    int lane = threadIdx.x & 63;
    int wid = threadIdx.x >> 6;
    int q = lane >> 4;
    int i = lane & 15;
    int node = blockIdx.x * 16 + wid * 4 + q;
    if (node >= n) return;
    const bool fv = (i < F4);
    float di = dinv[node];
    float4 acc = make_float4(0.f, 0.f, 0.f, 0.f);
    if (fv) {
        ushort4 hv = h4[(size_t)node * F4 + i];
        float4 bv = ((const float4*)b)[i];
        float d2 = di * di;
        acc.x = fmaf(bf2f(hv.x), d2, bv.x);
        acc.y = fmaf(bf2f(hv.y), d2, bv.y);
        acc.z = fmaf(bf2f(hv.z), d2, bv.z);
        acc.w = fmaf(bf2f(hv.w), d2, bv.w);
    }
    int r0 = rowptr[node];
    int cnt = deg[node];
    for (int j0 = 0; j0 < cnt; j0 += 16) {
#pragma unroll
        for (int t = 0; t < 16; ++t) {
            int idx = j0 + t;
            if (idx < cnt) {              // quarter-uniform guard
                int2 ew = adjw[r0 + idx]; // broadcast within quarter
                float wt = __int_as_float(ew.y);
                if (fv) {
                    ushort4 hv = h4[(size_t)ew.x * F4 + i];
                    acc.x = fmaf(bf2f(hv.x), wt, acc.x);
                    acc.y = fmaf(bf2f(hv.y), wt, acc.y);
                    acc.z = fmaf(bf2f(hv.z), wt, acc.z);
                    acc.w = fmaf(bf2f(hv.w), wt, acc.w);
                }
            }
        }
    }
    if (fv) ((float4*)out)[(size_t)node * F4 + i] = acc;
}

// ---------------- log_softmax over C cols, one wave per row ------------------
template <int C>
__global__ void logsoftmax_kernel(float* __restrict__ out, int n) {
    int wave = threadIdx.x >> 6;
    int lane = threadIdx.x & 63;
    int row = blockIdx.x * 4 + wave;
    if (row >= n) return;
    float v = (lane < C) ? out[(size_t)row * C + lane] : -INFINITY;
    float m = v;
#pragma unroll
    for (int off = 32; off >= 1; off >>= 1) m = fmaxf(m, __shfl_xor(m, off, 64));
    float e = (lane < C) ? expf(v - m) : 0.0f;
    float s = e;
#pragma unroll
    for (int off = 32; off >= 1; off >>= 1) s += __shfl_xor(s, off, 64);
    if (lane < C) out[(size_t)row * C + lane] = v - m - logf(s);
}

extern "C" void kernel_launch(void* const* d_in, const int* in_sizes, int n_in,
                              void* d_out, int out_size, void* d_ws, size_t ws_size,
                              hipStream_t stream) {
    const float* x  = (const float*)d_in[0];
    const int*   ei = (const int*)d_in[1];
    const float* W0 = (const float*)d_in[2];
    const float* b0 = (const float*)d_in[3];
    const float* W1 = (const float*)d_in[4];
    const float* b1 = (const float*)d_in[5];
    const float* W2 = (const float*)d_in[6];
    const float* b2 = (const float*)d_in[7];
    float* out = (float*)d_out;

    const int H   = in_sizes[3];            // 64
    const int FIN = in_sizes[2] / H;        // 64
    const int n   = in_sizes[0] / FIN;      // 50000
    const int E   = in_sizes[1] / 2;        // 800000
    (void)FIN;

    const int* srcp = ei;
    const int* dstp = ei + E;

    char* ws = (char*)d_ws;
    size_t off = 0;
    int*   deg    = (int*)(ws + off);   off += ws_align((size_t)n * 4);
    int*   rowptr = (int*)(ws + off);   off += ws_align((size_t)n * 4);
    int*   bsum   = (int*)(ws + off);   off += ws_align(256 * 4);
    float* dinv   = (float*)(ws + off); off += ws_align((size_t)n * 4);
    int*   pos    = (int*)(ws + off);   off += ws_align((size_t)E * 4);
    int2*  adjw   = (int2*)(ws + off);  off += ws_align((size_t)E * 8);
    unsigned int* hb = (unsigned int*)(ws + off); off += ws_align((size_t)n * H * 2);
    float* bufA   = (float*)(ws + off); off += ws_align((size_t)n * H * 4);
    unsigned short* wf0 = (unsigned short*)(ws + off); off += ws_align(4 * 2 * 64 * 8 * 2);
    unsigned short* wf1 = (unsigned short*)(ws + off); off += ws_align(4 * 2 * 64 * 8 * 2);
    unsigned short* wf2 = (unsigned short*)(ws + off); off += ws_align(3 * 2 * 64 * 8 * 2);

    // CSR build (deg zeroed by kernel; pos needs no init)
    zero_kernel<<<(n + 255) / 256, 256, 0, stream>>>(deg, n);
    deg_pos_kernel<<<(E + 255) / 256, 256, 0, stream>>>(dstp, E, deg, pos);
    dinv_kernel<<<(n + 255) / 256, 256, 0, stream>>>(deg, dinv, n);
    int nscan = (n + 1023) / 1024;  // 49
    scan1_kernel<<<nscan, 256, 0, stream>>>(deg, bsum, n);
    scan2_kernel<<<1, 256, 0, stream>>>(bsum, nscan);
    scan3_kernel<<<nscan, 256, 0, stream>>>(deg, bsum, rowptr, n);
    fill_kernel<<<(E + 255) / 256, 256, 0, stream>>>(srcp, dstp, pos, dinv, rowptr, adjw, E);

    // W fragment packing (tiny)
    wconv_kernel<64, 4><<<1, 256, 0, stream>>>(W0, wf0);
    wconv_kernel<64, 4><<<1, 256, 0, stream>>>(W1, wf1);
    wconv_kernel<40, 3><<<1, 256, 0, stream>>>(W2, wf2);

    const int MT = 2;  // row-tiles per wave
    int tiles = (n + 15) / 16;                        // 3125
    int gemm_grid = (tiles + 4 * MT - 1) / (4 * MT);  // 391
    int node_grid = (n + 15) / 16;                    // 16 nodes/block

    // layer 0
    gemm_mfma_kernel<64, 4, false, MT><<<gemm_grid, 256, 0, stream>>>(x, wf0, hb, n);
    gather_bf16_kernel<64><<<node_grid, 256, 0, stream>>>(rowptr, deg, adjw, (const ushort4*)hb, dinv, b0, bufA, n);
    // layer 1
    gemm_mfma_kernel<64, 4, true, MT><<<gemm_grid, 256, 0, stream>>>(bufA, wf1, hb, n);
    gather_bf16_kernel<64><<<node_grid, 256, 0, stream>>>(rowptr, deg, adjw, (const ushort4*)hb, dinv, b1, bufA, n);
    // layer 2
    gemm_mfma_kernel<40, 3, true, MT><<<gemm_grid, 256, 0, stream>>>(bufA, wf2, hb, n);
    gather_bf16_kernel<40><<<node_grid, 256, 0, stream>>>(rowptr, deg, adjw, (const ushort4*)hb, dinv, b2, out, n);
    logsoftmax_kernel<40><<<(n + 3) / 4, 256, 0, stream>>>(out, n);
}

// Round 7
// 205.787 us; speedup vs baseline: 1.5083x; 1.0807x over previous
//
#include <hip/hip_runtime.h>
#include <math.h>

static inline size_t ws_align(size_t x) { return (x + 255) & ~size_t(255); }

typedef float f32x4 __attribute__((ext_vector_type(4)));
typedef short bf16x8 __attribute__((ext_vector_type(8)));

__device__ inline unsigned int bf16rne(float f) {
    unsigned int u = __float_as_uint(f);
    u += 0x7FFFu + ((u >> 16) & 1u);
    return u >> 16;
}
__device__ inline float bf2f(unsigned short u) {
    return __uint_as_float(((unsigned int)u) << 16);
}

// ---------------- zero deg ----------------
__global__ void zero_kernel(int* __restrict__ p, int n) {
    int i = blockIdx.x * blockDim.x + threadIdx.x;
    if (i < n) p[i] = 0;
}

// ---------------- degree histogram + per-edge slot ----------------
__global__ void deg_pos_kernel(const int* __restrict__ dst, int E,
                               int* __restrict__ deg, int* __restrict__ pos) {
    int e = blockIdx.x * blockDim.x + threadIdx.x;
    if (e < E) pos[e] = atomicAdd(&deg[dst[e]], 1);
}

__global__ void dinv_kernel(const int* __restrict__ deg, float* __restrict__ dinv, int n) {
    int i = blockIdx.x * blockDim.x + threadIdx.x;
    if (i < n) dinv[i] = rsqrtf((float)(deg[i] + 1));  // +1 self-loop
}

// ---------------- exclusive scan of deg -> rowptr (1024 elems/block) ----------
__global__ void scan1_kernel(const int* __restrict__ deg, int* __restrict__ bsum, int n) {
    __shared__ int sdata[256];
    int base = blockIdx.x * 1024;
    int sum = 0;
    for (int i = threadIdx.x; i < 1024; i += 256) {
        int idx = base + i;
        if (idx < n) sum += deg[idx];
    }
    sdata[threadIdx.x] = sum;
    __syncthreads();
    for (int s = 128; s > 0; s >>= 1) {
        if (threadIdx.x < s) sdata[threadIdx.x] += sdata[threadIdx.x + s];
        __syncthreads();
    }
    if (threadIdx.x == 0) bsum[blockIdx.x] = sdata[0];
}

__global__ void scan2_kernel(int* __restrict__ bsum, int nb) {  // nb <= 256, 1 block
    __shared__ int sdata[256];
    int v = (threadIdx.x < nb) ? bsum[threadIdx.x] : 0;
    sdata[threadIdx.x] = v;
    __syncthreads();
    for (int off = 1; off < 256; off <<= 1) {
        int t = (threadIdx.x >= off) ? sdata[threadIdx.x - off] : 0;
        __syncthreads();
        sdata[threadIdx.x] += t;
        __syncthreads();
    }
    if (threadIdx.x < nb) bsum[threadIdx.x] = sdata[threadIdx.x] - v;  // exclusive
}

__global__ void scan3_kernel(const int* __restrict__ deg, const int* __restrict__ bsum,
                             int* __restrict__ rowptr, int n) {
    __shared__ int ssum[256];
    int base = blockIdx.x * 1024 + threadIdx.x * 4;
    int v[4];
    int s = 0;
#pragma unroll
    for (int k = 0; k < 4; ++k) {
        int idx = base + k;
        v[k] = (idx < n) ? deg[idx] : 0;
        s += v[k];
    }
    ssum[threadIdx.x] = s;
    __syncthreads();
    for (int off = 1; off < 256; off <<= 1) {
        int t = (threadIdx.x >= off) ? ssum[threadIdx.x - off] : 0;
        __syncthreads();
        ssum[threadIdx.x] += t;
        __syncthreads();
    }
    int ex = (threadIdx.x > 0 ? ssum[threadIdx.x - 1] : 0) + bsum[blockIdx.x];
#pragma unroll
    for (int k = 0; k < 4; ++k) {
        int idx = base + k;
        if (idx < n) rowptr[idx] = ex;
        ex += v[k];
    }
}

// ---------------- CSR fill (no atomic, adj only): adj[rowptr[d]+pos[e]] = src -
__global__ void fill_kernel(const int* __restrict__ src, const int* __restrict__ dst,
                            const int* __restrict__ pos, const int* __restrict__ rowptr,
                            int* __restrict__ adj, int E) {
    int e = blockIdx.x * blockDim.x + threadIdx.x;
    if (e >= E) return;
    adj[rowptr[dst[e]] + pos[e]] = src[e];
}

// ---------------- W -> MFMA B-fragment layout (bf16), zero-padded ------------
template <int FOUT, int CT>
__global__ void wconv_kernel(const float* __restrict__ W, unsigned short* __restrict__ wf) {
    for (int idx = threadIdx.x; idx < CT * 2 * 64 * 8; idx += 256) {
        int j = idx & 7;
        int lane = (idx >> 3) & 63;
        int kh = (idx >> 9) & 1;
        int ct = idx >> 10;
        int k = kh * 32 + ((lane >> 4) * 8) + j;
        int col = ct * 16 + (lane & 15);
        float v = (col < FOUT) ? W[k * FOUT + col] : 0.0f;
        wf[idx] = (unsigned short)bf16rne(v);
    }
}

// ---------------- MFMA dense transform -> hs = dinv * (in @ W), bf16 --------
// FIN fixed at 64. One wave = 16-row tile x FOUT cols; MT tiles per wave.
// IN_BF16: input rows already relu'd bf16; else raw fp32 (layer 0).
template <int FOUT, int CT, bool IN_BF16, int MT>
__global__ void gemm_mfma_kernel(const void* __restrict__ in_, const unsigned short* __restrict__ wf,
                                 const float* __restrict__ dinv, unsigned int* __restrict__ hs32,
                                 int n) {
    int lane = threadIdx.x & 63;
    int tile0 = (blockIdx.x * 4 + (threadIdx.x >> 6)) * MT;
    if (tile0 * 16 >= n) return;
    bf16x8 bfrag[CT][2];
#pragma unroll
    for (int ct = 0; ct < CT; ++ct)
#pragma unroll
        for (int kh = 0; kh < 2; ++kh)
            bfrag[ct][kh] = *(const bf16x8*)(wf + ((size_t)(ct * 2 + kh) * 64 + lane) * 8);

    int rloc = lane & 15;   // A row within tile
    int koct = lane >> 4;   // k octet 0..3
    for (int t = 0; t < MT; ++t) {
        int rbase = (tile0 + t) * 16;
        if (rbase >= n) break;
        int r = rbase + rloc;
        int rc = (r < n) ? r : (n - 1);
        bf16x8 af0, af1;
        if (IN_BF16) {
            const unsigned short* inb = (const unsigned short*)in_;
            af0 = *(const bf16x8*)(inb + (size_t)rc * 64 + koct * 8);
            af1 = *(const bf16x8*)(inb + (size_t)rc * 64 + 32 + koct * 8);
        } else {
            const float* inf = (const float*)in_;
            const float* ap = inf + (size_t)rc * 64 + koct * 8;
            float av[16];
            *(float4*)(av + 0)  = *(const float4*)(ap + 0);
            *(float4*)(av + 4)  = *(const float4*)(ap + 4);
            *(float4*)(av + 8)  = *(const float4*)(ap + 32);
            *(float4*)(av + 12) = *(const float4*)(ap + 36);
#pragma unroll
            for (int j = 0; j < 8; ++j) {
                af0[j] = (short)bf16rne(av[j]);
                af1[j] = (short)bf16rne(av[8 + j]);
            }
        }
#pragma unroll
        for (int ct = 0; ct < CT; ++ct) {
            f32x4 acc = {0.0f, 0.0f, 0.0f, 0.0f};
            acc = __builtin_amdgcn_mfma_f32_16x16x32_bf16(af0, bfrag[ct][0], acc, 0, 0, 0);
            acc = __builtin_amdgcn_mfma_f32_16x16x32_bf16(af1, bfrag[ct][1], acc, 0, 0, 0);
            int col = ct * 16 + rloc;  // D col = lane&15
#pragma unroll
            for (int reg = 0; reg < 4; ++reg) {
                int row = rbase + koct * 4 + reg;  // D row = (lane>>4)*4+reg
                float dd = dinv[(row < n) ? row : (n - 1)];
                float v = acc[reg] * dd;
                float po = __shfl_xor(v, 1, 64);   // partner column (lane^1)
                if (row < n && ((lane & 1) == 0) && col < FOUT) {
                    hs32[((size_t)row * FOUT + col) >> 1] = bf16rne(v) | (bf16rne(po) << 16);
                }
            }
        }
    }
}

// ---------------- gather-aggregate: quarter (16 lanes) per node --------------
// t = dinv[v]*(hs[v] + sum_{e: dst=v} hs[src_e]) + b
// MODE 0: store bf16(relu(t))  (next layer input)
// MODE 1: fused log_softmax, store fp32 to out
template <int F, int MODE>  // F % 4 == 0, F <= 64
__global__ void gather_kernel(const int* __restrict__ rowptr, const int* __restrict__ deg,
                              const int* __restrict__ adj, const unsigned short* __restrict__ hs,
                              const float* __restrict__ dinv, const float* __restrict__ b,
                              void* __restrict__ outp, int n) {
    const int F4 = F / 4;
    int lane = threadIdx.x & 63;
    int wid = threadIdx.x >> 6;
    int q = lane >> 4;
    int i = lane & 15;
    int node = blockIdx.x * 16 + wid * 4 + q;
    if (node >= n) return;
    const bool fv = (i < F4);
    const ushort4* h4 = (const ushort4*)hs;
    float4 acc = make_float4(0.f, 0.f, 0.f, 0.f);
    if (fv) {
        ushort4 hv = h4[(size_t)node * F4 + i];   // self term
        acc.x = bf2f(hv.x); acc.y = bf2f(hv.y); acc.z = bf2f(hv.z); acc.w = bf2f(hv.w);
    }
    int r0 = rowptr[node];
    int cnt = deg[node];
    for (int j0 = 0; j0 < cnt; j0 += 16) {
#pragma unroll
        for (int t = 0; t < 16; ++t) {
            int idx = j0 + t;
            if (idx < cnt) {              // quarter-uniform guard
                int s = adj[r0 + idx];    // broadcast within quarter
                if (fv) {
                    ushort4 hv = h4[(size_t)s * F4 + i];
                    acc.x += bf2f(hv.x);
                    acc.y += bf2f(hv.y);
                    acc.z += bf2f(hv.z);
                    acc.w += bf2f(hv.w);
                }
            }
        }
    }
    float dd = dinv[node];
    float4 tv = make_float4(0.f, 0.f, 0.f, 0.f);
    if (fv) {
        float4 bv = ((const float4*)b)[i];
        tv.x = fmaf(acc.x, dd, bv.x);
        tv.y = fmaf(acc.y, dd, bv.y);
        tv.z = fmaf(acc.z, dd, bv.z);
        tv.w = fmaf(acc.w, dd, bv.w);
    }
    if (MODE == 0) {
        if (fv) {
            ushort4 o;
            o.x = (unsigned short)bf16rne(fmaxf(tv.x, 0.0f));
            o.y = (unsigned short)bf16rne(fmaxf(tv.y, 0.0f));
            o.z = (unsigned short)bf16rne(fmaxf(tv.z, 0.0f));
            o.w = (unsigned short)bf16rne(fmaxf(tv.w, 0.0f));
            ((ushort4*)outp)[(size_t)node * F4 + i] = o;
        }
    } else {
        // log-softmax over the quarter's F values (width-16 reduction)
        float m = fv ? fmaxf(fmaxf(tv.x, tv.y), fmaxf(tv.z, tv.w)) : -INFINITY;
#pragma unroll
        for (int off = 8; off >= 1; off >>= 1) m = fmaxf(m, __shfl_xor(m, off, 16));
        float es = fv ? (expf(tv.x - m) + expf(tv.y - m) + expf(tv.z - m) + expf(tv.w - m)) : 0.0f;
#pragma unroll
        for (int off = 8; off >= 1; off >>= 1) es += __shfl_xor(es, off, 16);
        float ls = logf(es);
        if (fv) {
            float4 o = make_float4(tv.x - m - ls, tv.y - m - ls, tv.z - m - ls, tv.w - m - ls);
            ((float4*)outp)[(size_t)node * F4 + i] = o;
        }
    }
}

extern "C" void kernel_launch(void* const* d_in, const int* in_sizes, int n_in,
                              void* d_out, int out_size, void* d_ws, size_t ws_size,
                              hipStream_t stream) {
    const float* x  = (const float*)d_in[0];
    const int*   ei = (const int*)d_in[1];
    const float* W0 = (const float*)d_in[2];
    const float* b0 = (const float*)d_in[3];
    const float* W1 = (const float*)d_in[4];
    const float* b1 = (const float*)d_in[5];
    const float* W2 = (const float*)d_in[6];
    const float* b2 = (const float*)d_in[7];
    float* out = (float*)d_out;

    const int H   = in_sizes[3];            // 64
    const int FIN = in_sizes[2] / H;        // 64
    const int n   = in_sizes[0] / FIN;      // 50000
    const int E   = in_sizes[1] / 2;        // 800000
    (void)FIN;

    const int* srcp = ei;
    const int* dstp = ei + E;

    char* ws = (char*)d_ws;
    size_t off = 0;
    int*   deg    = (int*)(ws + off);   off += ws_align((size_t)n * 4);
    int*   rowptr = (int*)(ws + off);   off += ws_align((size_t)n * 4);
    int*   bsum   = (int*)(ws + off);   off += ws_align(256 * 4);
    float* dinv   = (float*)(ws + off); off += ws_align((size_t)n * 4);
    int*   pos    = (int*)(ws + off);   off += ws_align((size_t)E * 4);
    int*   adj    = (int*)(ws + off);   off += ws_align((size_t)E * 4);
    unsigned short* hsA  = (unsigned short*)(ws + off); off += ws_align((size_t)n * H * 2);
    unsigned short* actB = (unsigned short*)(ws + off); off += ws_align((size_t)n * H * 2);
    unsigned short* wf0 = (unsigned short*)(ws + off); off += ws_align(4 * 2 * 64 * 8 * 2);
    unsigned short* wf1 = (unsigned short*)(ws + off); off += ws_align(4 * 2 * 64 * 8 * 2);
    unsigned short* wf2 = (unsigned short*)(ws + off); off += ws_align(3 * 2 * 64 * 8 * 2);

    // CSR build (deg zeroed by kernel; pos needs no init)
    zero_kernel<<<(n + 255) / 256, 256, 0, stream>>>(deg, n);
    deg_pos_kernel<<<(E + 255) / 256, 256, 0, stream>>>(dstp, E, deg, pos);
    dinv_kernel<<<(n + 255) / 256, 256, 0, stream>>>(deg, dinv, n);
    int nscan = (n + 1023) / 1024;  // 49
    scan1_kernel<<<nscan, 256, 0, stream>>>(deg, bsum, n);
    scan2_kernel<<<1, 256, 0, stream>>>(bsum, nscan);
    scan3_kernel<<<nscan, 256, 0, stream>>>(deg, bsum, rowptr, n);
    fill_kernel<<<(E + 255) / 256, 256, 0, stream>>>(srcp, dstp, pos, rowptr, adj, E);

    // W fragment packing (tiny)
    wconv_kernel<64, 4><<<1, 256, 0, stream>>>(W0, wf0);
    wconv_kernel<64, 4><<<1, 256, 0, stream>>>(W1, wf1);
    wconv_kernel<40, 3><<<1, 256, 0, stream>>>(W2, wf2);

    const int MT = 2;  // row-tiles per wave
    int tiles = (n + 15) / 16;                        // 3125
    int gemm_grid = (tiles + 4 * MT - 1) / (4 * MT);  // 391
    int node_grid = (n + 15) / 16;                    // 16 nodes/block

    // layer 0: x fp32 -> hsA ; gather -> actB (relu bf16)
    gemm_mfma_kernel<64, 4, false, MT><<<gemm_grid, 256, 0, stream>>>(x, wf0, dinv, (unsigned int*)hsA, n);
    gather_kernel<64, 0><<<node_grid, 256, 0, stream>>>(rowptr, deg, adj, hsA, dinv, b0, actB, n);
    // layer 1
    gemm_mfma_kernel<64, 4, true, MT><<<gemm_grid, 256, 0, stream>>>(actB, wf1, dinv, (unsigned int*)hsA, n);
    gather_kernel<64, 0><<<node_grid, 256, 0, stream>>>(rowptr, deg, adj, hsA, dinv, b1, actB, n);
    // layer 2: gemm -> hsA (n x 40) ; gather + fused log_softmax -> out
    gemm_mfma_kernel<40, 3, true, MT><<<gemm_grid, 256, 0, stream>>>(actB, wf2, dinv, (unsigned int*)hsA, n);
    gather_kernel<40, 1><<<node_grid, 256, 0, stream>>>(rowptr, deg, adj, hsA, dinv, b2, out, n);
}